// Round 10
// baseline (54.918 us; speedup 1.0000x reference)
//
#include <hip/hip_runtime.h>
#include <math.h>

#define BATCH 8
#define HH 192
#define WW 192
#define BIGF 1e10f
#define OH (HH - 10)               // 182
#define OW (WW - 10)               // 182
#define NEDTBLK (BATCH * HH)       // 1536
#define NENVBLK (BATCH * WW)       // 1536
#define NSSIMBLK (BATCH * OH)      // 1456

__device__ __forceinline__ float waveReduceAdd(float v) {
    #pragma unroll
    for (int o = 32; o > 0; o >>= 1) v += __shfl_down(v, o, 64);
    return v;
}

// Nearest set bit in a 192-bit mask (3x u64) to position x (round-7 proven).
__device__ __forceinline__ int nearestDist(const unsigned long long m0,
                                           const unsigned long long m1,
                                           const unsigned long long m2,
                                           int x) {
    const unsigned long long m[3] = {m0, m1, m2};
    const int wi = x >> 6, b = x & 63;
    int dL = 1 << 29;
    const unsigned long long low = m[wi] << (63 - b);
    if (low) dL = __clzll(low);
    else if (wi >= 1 && m[wi - 1]) dL = b + 1 + __clzll(m[wi - 1]);
    else if (wi == 2 && m[0]) dL = b + 65 + __clzll(m[0]);
    int dR = 1 << 29;
    const unsigned long long high = m[wi] >> b;
    if (high) dR = __ffsll((long long)high) - 1;
    else if (wi <= 1 && m[wi + 1]) dR = (64 - b) + __ffsll((long long)m[wi + 1]) - 1;
    else if (wi == 0 && m[2]) dR = (128 - b) + __ffsll((long long)m[2]) - 1;
    return min(dL, dR);
}

// Dispatch A: per-row 1D EDT via ballot; packed transposed records
// colminT[b][x][r] = {f32 logit, dfg | dbg<<8 | fg<<16}. Block 0 zeroes out[0]
// (stream order guarantees visibility to dispatch B's atomics).
__global__ void edtKernel(const float* __restrict__ pred,
                          const int* __restrict__ tgt,
                          uint2* __restrict__ colminT,
                          float* __restrict__ out) {
    __shared__ unsigned long long lmask[3];
    const int x = threadIdx.x;  // 0..191
    if (blockIdx.x == 0 && x == 0) out[0] = 0.0f;
    const int b = blockIdx.x / HH, r = blockIdx.x % HH;
    const float z = pred[(b * HH + r) * WW + x];   // coalesced
    const int t = tgt[(b * HH + r) * WW + x];      // coalesced
    const int fg = (t > 0) ? 1 : 0;
    const unsigned long long bal = __ballot(fg);
    if ((x & 63) == 0) lmask[x >> 6] = bal;
    __syncthreads();
    const unsigned long long f0 = lmask[0], f1 = lmask[1], f2 = lmask[2];
    int dfg = nearestDist(f0, f1, f2, x);
    int dbg = nearestDist(~f0, ~f1, ~f2, x);
    dfg = min(dfg, 255);   // 255 = "none in row" sentinel (real d <= 191)
    dbg = min(dbg, 255);
    colminT[((size_t)b * WW + x) * HH + r] =
        make_uint2(__float_as_uint(z), (unsigned)(dfg | (dbg << 8) | (fg << 16)));
}

// Dispatch B: blocks [0,NENVBLK) = column envelope + BCE/focal/boundary
// (one column each); blocks [NENVBLK,..) = SSIM (one output row each).
// Each block fire-and-forget atomicAdd's its pre-scaled partial into out[0].
__global__ void lossKernel(const float* __restrict__ pred,
                           const int* __restrict__ tgt,
                           const uint2* __restrict__ colminT,
                           float* __restrict__ out) {
    __shared__ __align__(16) float smem[5 * WW];
    __shared__ float red[3];
    const int x = threadIdx.x;  // 0..191
    const int wid = x >> 6;

    if (blockIdx.x < NENVBLK) {
        // ================= envelope + fused losses (round-7 proven) ===============
        const int b = blockIdx.x / WW, cx = blockIdx.x % WW;
        const int y = x;

        float2* scfb = (float2*)smem;
        const uint2 v = colminT[((size_t)b * WW + cx) * HH + y];  // coalesced 8B/lane
        const int dfg = v.y & 255, dbg = (v.y >> 8) & 255;
        scfb[y] = make_float2(dfg == 255 ? BIGF : (float)(dfg * dfg),
                              dbg == 255 ? BIGF : (float)(dbg * dbg));
        __syncthreads();

        float o0 = BIGF, o1 = BIGF, o2 = BIGF, o3 = BIGF;
        float i0 = BIGF, i1 = BIGF, i2 = BIGF, i3 = BIGF;
        const float fy = (float)y;
        #pragma unroll 6
        for (int rp = 0; rp < HH; rp += 4) {
            const float4 v0 = *(const float4*)&scfb[rp];
            const float4 v1 = *(const float4*)&scfb[rp + 2];
            const float e0 = fy - (float)rp;
            const float e1 = fy - (float)(rp + 1);
            const float e2 = fy - (float)(rp + 2);
            const float e3 = fy - (float)(rp + 3);
            o0 = fminf(o0, fmaf(e0, e0, v0.x)); i0 = fminf(i0, fmaf(e0, e0, v0.y));
            o1 = fminf(o1, fmaf(e1, e1, v0.z)); i1 = fminf(i1, fmaf(e1, e1, v0.w));
            o2 = fminf(o2, fmaf(e2, e2, v1.x)); i2 = fminf(i2, fmaf(e2, e2, v1.y));
            o3 = fminf(o3, fmaf(e3, e3, v1.z)); i3 = fminf(i3, fmaf(e3, e3, v1.w));
        }
        const float d2o = fminf(fminf(o0, o1), fminf(o2, o3));
        const float d2i = fminf(fminf(i0, i1), fminf(i2, i3));

        // empty-mask fallback folds into the clamp: min(1e10, maxd2) -> maxd exactly
        const float maxd2 = (float)((HH - 1) * (HH - 1) + (WW - 1) * (WW - 1));
        const float dist_out = sqrtf(fminf(d2o, maxd2));
        const float dist_in  = sqrtf(fminf(d2i, maxd2));

        const float tf = (float)((v.y >> 16) & 255);
        const float phi = (tf > 0.5f) ? -dist_in : dist_out;
        const float z = __uint_as_float(v.x);
        const float p = 1.0f / (1.0f + __expf(-z));

        // boundary
        const float wgt = __expf(-fabsf(phi) * 0.1f);
        const float bnd = wgt * fabsf(phi * p);
        // bce (log clamped at -100 like torch BCELoss)
        const float logp   = fmaxf(__logf(p), -100.0f);
        const float log1mp = fmaxf(__logf(1.0f - p), -100.0f);
        const float bce = -(tf * logp + (1.0f - tf) * log1mp);
        // focal
        const float pc = fminf(fmaxf(p, 1e-6f), 1.0f - 1e-6f);
        const float pt = pc * tf + (1.0f - pc) * (1.0f - tf);
        const float at = 0.25f * tf + 0.75f * (1.0f - tf);
        const float om = 1.0f - pt;
        const float focal = -at * om * om * __logf(pt);

        const float s = waveReduceAdd(bce + focal + bnd);
        if ((x & 63) == 0) red[wid] = s;
        __syncthreads();
        if (x == 0) {
            const float N1 = (float)(BATCH * HH * WW);
            atomicAdd(out, (red[0] + red[1] + red[2]) * (1.0f / N1));  // no return: no wait
        }
    } else {
        // ================= SSIM (round-7 proven, 1 output row/block) ==============
        const int blk = blockIdx.x - NENVBLK;
        const int b = blk / OH, yo = blk % OH;

        float g[11];
        {
            float s = 0.0f;
            #pragma unroll
            for (int k = 0; k < 11; ++k) {
                const float d = (float)(k - 5);
                g[k] = __expf(-d * d / 4.5f);
                s += g[k];
            }
            const float inv = 1.0f / s;
            #pragma unroll
            for (int k = 0; k < 11; ++k) g[k] *= inv;
        }

        float* sp = smem;
        float* st = smem + WW;
        float* spp = smem + 2 * WW;
        float* stt = smem + 3 * WW;
        float* spt = smem + 4 * WW;

        float ap = 0, at = 0, app = 0, att = 0, apt = 0;
        #pragma unroll
        for (int k = 0; k < 11; ++k) {
            const int row = yo + k;
            const float z = pred[(b * HH + row) * WW + x];
            const float p = 1.0f / (1.0f + __expf(-z));
            const float t = (float)tgt[(b * HH + row) * WW + x];
            const float gk = g[k];
            ap += gk * p; at += gk * t;
            app += gk * p * p; att += gk * t * t; apt += gk * p * t;
        }
        sp[x] = ap; st[x] = at; spp[x] = app; stt[x] = att; spt[x] = apt;
        __syncthreads();

        float term = 0.0f;
        if (x < OW) {
            float mx = 0, my = 0, mxx = 0, myy = 0, mxy = 0;
            #pragma unroll
            for (int k = 0; k < 11; ++k) {
                mx += g[k] * sp[x + k];  my += g[k] * st[x + k];
                mxx += g[k] * spp[x + k]; myy += g[k] * stt[x + k];
                mxy += g[k] * spt[x + k];
            }
            const float C1 = 1e-4f, C2 = 9e-4f;
            const float sx = mxx - mx * mx, sy = myy - my * my, sxy = mxy - mx * my;
            const float num = (2.0f * mx * my + C1) * (2.0f * sxy + C2);
            const float den = (mx * mx + my * my + C1) * (sx + sy + C2);
            term = num / den;
        }
        const float s = waveReduceAdd(term);
        if ((x & 63) == 0) red[wid] = s;
        __syncthreads();
        if (x == 0) {
            const float N2 = (float)(BATCH * OH * OW);
            atomicAdd(out, (red[0] + red[1] + red[2]) * (1.0f / N2));  // no return: no wait
        }
    }
}

extern "C" void kernel_launch(void* const* d_in, const int* in_sizes, int n_in,
                              void* d_out, int out_size, void* d_ws, size_t ws_size,
                              hipStream_t stream) {
    const float* pred = (const float*)d_in[0];
    const int* tgt = (const int*)d_in[1];

    uint2* colminT = (uint2*)d_ws;   // 8*192*192*8 = 2359296 B
    float* out = (float*)d_out;

    edtKernel<<<NEDTBLK, WW, 0, stream>>>(pred, tgt, colminT, out);
    lossKernel<<<NENVBLK + NSSIMBLK, WW, 0, stream>>>(pred, tgt, colminT, out);
}

// Round 11
// 23.288 us; speedup vs baseline: 2.3582x; 2.3582x over previous
//
#include <hip/hip_runtime.h>
#include <math.h>

#define BATCH 8
#define HH 192
#define WW 192
#define BIGF 1e10f
#define OH (HH - 10)                                  // 182
#define OW (WW - 10)                                  // 182
#define SSIM_ROWS 4
#define SSIM_BPI ((OH + SSIM_ROWS - 1) / SSIM_ROWS)   // 46
#define NSSIMBLK (BATCH * SSIM_BPI)                   // 368
#define NMASKBLK (BATCH * HH)                         // 1536
#define NENVBLK (BATCH * WW)                          // 1536

__device__ __forceinline__ float waveReduceAdd(float v) {
    #pragma unroll
    for (int o = 32; o > 0; o >>= 1) v += __shfl_down(v, o, 64);
    return v;
}

// Nearest set bit in a 192-bit mask (3x u64) to position x (round-7/8 proven).
__device__ __forceinline__ int nearestDist(const unsigned long long m0,
                                           const unsigned long long m1,
                                           const unsigned long long m2,
                                           int x) {
    const unsigned long long m[3] = {m0, m1, m2};
    const int wi = x >> 6, b = x & 63;
    int dL = 1 << 29;
    const unsigned long long low = m[wi] << (63 - b);
    if (low) dL = __clzll(low);
    else if (wi >= 1 && m[wi - 1]) dL = b + 1 + __clzll(m[wi - 1]);
    else if (wi == 2 && m[0]) dL = b + 65 + __clzll(m[0]);
    int dR = 1 << 29;
    const unsigned long long high = m[wi] >> b;
    if (high) dR = __ffsll((long long)high) - 1;
    else if (wi <= 1 && m[wi + 1]) dR = (64 - b) + __ffsll((long long)m[wi + 1]) - 1;
    else if (wi == 0 && m[2]) dR = (128 - b) + __ffsll((long long)m[2]) - 1;
    return min(dL, dR);
}

// Dispatch A: blocks [0,NSSIMBLK) = SSIM, 4 output rows each (R9-proven math,
// plain-store partials). Blocks [NSSIMBLK,..) = row fg-bitmask build (ballot only;
// 3 u64 per row). No colminT, no atomics.
__global__ void prepKernel(const float* __restrict__ pred,
                           const int* __restrict__ tgt,
                           unsigned long long* __restrict__ mask,  // [B][3][HH]
                           float* __restrict__ ssimPart) {
    const int x = threadIdx.x;  // 0..191

    if (blockIdx.x >= NSSIMBLK) {
        // ---- row mask: one row per block ----
        const int blk = blockIdx.x - NSSIMBLK;
        const int b = blk / HH, r = blk % HH;
        const int t = tgt[(b * HH + r) * WW + x];      // coalesced
        const unsigned long long bal = __ballot(t > 0);
        if ((x & 63) == 0) mask[((size_t)b * 3 + (x >> 6)) * HH + r] = bal;
        return;
    }

    // ---- SSIM: 4 output rows per block ----
    __shared__ __align__(16) float smem[SSIM_ROWS * 5 * WW];  // 15360 B
    __shared__ float red1[3];
    const int blk = blockIdx.x;
    const int b = blk / SSIM_BPI;
    const int r0 = (blk % SSIM_BPI) * SSIM_ROWS;

    float g[11];
    {
        float s = 0.0f;
        #pragma unroll
        for (int k = 0; k < 11; ++k) {
            const float d = (float)(k - 5);
            g[k] = __expf(-d * d / 4.5f);
            s += g[k];
        }
        const float inv = 1.0f / s;
        #pragma unroll
        for (int k = 0; k < 11; ++k) g[k] *= inv;
    }

    float acc[SSIM_ROWS][5];
    #pragma unroll
    for (int o = 0; o < SSIM_ROWS; ++o)
        #pragma unroll
        for (int s = 0; s < 5; ++s) acc[o][s] = 0.0f;

    #pragma unroll
    for (int j = 0; j < SSIM_ROWS + 10; ++j) {
        const int row = r0 + j;
        float p = 0.0f, t = 0.0f;
        if (row < HH) {
            const float z = pred[(b * HH + row) * WW + x];
            p = 1.0f / (1.0f + __expf(-z));
            t = (float)tgt[(b * HH + row) * WW + x];
        }
        const float pp = p * p, tt = t * t, pt = p * t;
        #pragma unroll
        for (int o = 0; o < SSIM_ROWS; ++o) {
            const int k = j - o;
            if (k >= 0 && k <= 10) {
                const float gk = g[k];
                acc[o][0] += gk * p;  acc[o][1] += gk * t;
                acc[o][2] += gk * pp; acc[o][3] += gk * tt; acc[o][4] += gk * pt;
            }
        }
    }
    #pragma unroll
    for (int o = 0; o < SSIM_ROWS; ++o)
        #pragma unroll
        for (int s = 0; s < 5; ++s) smem[(o * 5 + s) * WW + x] = acc[o][s];
    __syncthreads();

    float term = 0.0f;
    if (x < OW) {
        #pragma unroll
        for (int o = 0; o < SSIM_ROWS; ++o) {
            if (r0 + o < OH) {   // uniform per block
                float mx = 0, my = 0, mxx = 0, myy = 0, mxy = 0;
                #pragma unroll
                for (int k = 0; k < 11; ++k) {
                    mx  += g[k] * smem[(o * 5 + 0) * WW + x + k];
                    my  += g[k] * smem[(o * 5 + 1) * WW + x + k];
                    mxx += g[k] * smem[(o * 5 + 2) * WW + x + k];
                    myy += g[k] * smem[(o * 5 + 3) * WW + x + k];
                    mxy += g[k] * smem[(o * 5 + 4) * WW + x + k];
                }
                const float C1 = 1e-4f, C2 = 9e-4f;
                const float sx = mxx - mx * mx, sy = myy - my * my, sxy = mxy - mx * my;
                const float num = (2.0f * mx * my + C1) * (2.0f * sxy + C2);
                const float den = (mx * mx + my * my + C1) * (sx + sy + C2);
                term += num / den;
            }
        }
    }
    const float s = waveReduceAdd(term);
    const int wid = x >> 6;
    if ((x & 63) == 0) red1[wid] = s;
    __syncthreads();
    if (x == 0) ssimPart[blk] = red1[0] + red1[1] + red1[2];
}

// Dispatch B: one block per (b, column cx). Thread y: load its row's 3 mask words
// (coalesced u64), nearestDist inline (no colminT), envelope from LDS broadcasts,
// fused losses, combined partial via plain store.
__global__ void envKernel(const float* __restrict__ pred,
                          const unsigned long long* __restrict__ mask,
                          float* __restrict__ envPart) {
    const int b = blockIdx.x / WW, cx = blockIdx.x % WW;
    const int y = threadIdx.x;  // 0..191

    __shared__ __align__(16) float scf[HH];
    __shared__ __align__(16) float scb[HH];
    __shared__ float red[3];

    const unsigned long long m0 = mask[((size_t)b * 3 + 0) * HH + y];
    const unsigned long long m1 = mask[((size_t)b * 3 + 1) * HH + y];
    const unsigned long long m2 = mask[((size_t)b * 3 + 2) * HH + y];
    const float z = pred[(b * HH + y) * WW + cx];   // uncoalesced; issued early

    const int dfg = nearestDist(m0, m1, m2, cx);
    const int dbg = nearestDist(~m0, ~m1, ~m2, cx);
    scf[y] = (dfg >= WW) ? BIGF : (float)(dfg * dfg);
    scb[y] = (dbg >= WW) ? BIGF : (float)(dbg * dbg);
    const unsigned long long fw = (cx < 64) ? m0 : (cx < 128) ? m1 : m2;
    const float tf = (float)((fw >> (cx & 63)) & 1ull);
    __syncthreads();

    float o0 = BIGF, o1 = BIGF, o2 = BIGF, o3 = BIGF;
    float i0 = BIGF, i1 = BIGF, i2 = BIGF, i3 = BIGF;
    const float fy = (float)y;
    #pragma unroll 6
    for (int rp = 0; rp < HH; rp += 4) {
        const float4 vf = *(const float4*)&scf[rp];   // broadcast reads, conflict-free
        const float4 vb = *(const float4*)&scb[rp];
        const float e0 = fy - (float)rp;
        const float e1 = fy - (float)(rp + 1);
        const float e2 = fy - (float)(rp + 2);
        const float e3 = fy - (float)(rp + 3);
        o0 = fminf(o0, fmaf(e0, e0, vf.x)); i0 = fminf(i0, fmaf(e0, e0, vb.x));
        o1 = fminf(o1, fmaf(e1, e1, vf.y)); i1 = fminf(i1, fmaf(e1, e1, vb.y));
        o2 = fminf(o2, fmaf(e2, e2, vf.z)); i2 = fminf(i2, fmaf(e2, e2, vb.z));
        o3 = fminf(o3, fmaf(e3, e3, vf.w)); i3 = fminf(i3, fmaf(e3, e3, vb.w));
    }
    const float d2o = fminf(fminf(o0, o1), fminf(o2, o3));
    const float d2i = fminf(fminf(i0, i1), fminf(i2, i3));

    // empty-mask fallback folds into the clamp: min(1e10, maxd2) -> maxd exactly
    const float maxd2 = (float)((HH - 1) * (HH - 1) + (WW - 1) * (WW - 1));
    const float dist_out = sqrtf(fminf(d2o, maxd2));
    const float dist_in  = sqrtf(fminf(d2i, maxd2));

    const float phi = (tf > 0.5f) ? -dist_in : dist_out;
    const float p = 1.0f / (1.0f + __expf(-z));

    // boundary
    const float wgt = __expf(-fabsf(phi) * 0.1f);
    const float bnd = wgt * fabsf(phi * p);
    // bce (log clamped at -100 like torch BCELoss)
    const float logp   = fmaxf(__logf(p), -100.0f);
    const float log1mp = fmaxf(__logf(1.0f - p), -100.0f);
    const float bce = -(tf * logp + (1.0f - tf) * log1mp);
    // focal
    const float pc = fminf(fmaxf(p, 1e-6f), 1.0f - 1e-6f);
    const float pt = pc * tf + (1.0f - pc) * (1.0f - tf);
    const float at = 0.25f * tf + 0.75f * (1.0f - tf);
    const float om = 1.0f - pt;
    const float focal = -at * om * om * __logf(pt);

    const float s = waveReduceAdd(bce + focal + bnd);
    const int wid = y >> 6;
    if ((y & 63) == 0) red[wid] = s;
    __syncthreads();
    if (y == 0) envPart[blockIdx.x] = red[0] + red[1] + red[2];
}

// Dispatch C: final reduction + combine (fixed order -> deterministic)
__global__ void reduceKernel(const float* __restrict__ envPart,
                             const float* __restrict__ ssimPart,
                             float* __restrict__ out) {
    const int tid = threadIdx.x;  // 0..1023
    float s0 = 0, s3 = 0;
    for (int i = tid; i < NENVBLK; i += 1024) s0 += envPart[i];
    for (int i = tid; i < NSSIMBLK; i += 1024) s3 += ssimPart[i];
    s0 = waveReduceAdd(s0);
    s3 = waveReduceAdd(s3);
    __shared__ float red[16][2];
    const int wid = tid >> 6;
    if ((tid & 63) == 0) { red[wid][0] = s0; red[wid][1] = s3; }
    __syncthreads();
    if (tid == 0) {
        float t0 = 0, t3 = 0;
        #pragma unroll
        for (int w = 0; w < 16; ++w) { t0 += red[w][0]; t3 += red[w][1]; }
        const float N1 = (float)(BATCH * HH * WW);
        const float N2 = (float)(BATCH * OH * OW);
        out[0] = t0 / N1 + t3 / N2;
    }
}

extern "C" void kernel_launch(void* const* d_in, const int* in_sizes, int n_in,
                              void* d_out, int out_size, void* d_ws, size_t ws_size,
                              hipStream_t stream) {
    const float* pred = (const float*)d_in[0];
    const int* tgt = (const int*)d_in[1];

    float* ssimPart = (float*)d_ws;                               // 368*4 B
    float* envPart = (float*)((char*)d_ws + 4096);                // 1536*4 B
    unsigned long long* mask = (unsigned long long*)((char*)d_ws + 16384);  // 8*3*192*8 = 36864 B

    prepKernel<<<NSSIMBLK + NMASKBLK, WW, 0, stream>>>(pred, tgt, mask, ssimPart);
    envKernel<<<NENVBLK, WW, 0, stream>>>(pred, mask, envPart);
    reduceKernel<<<1, 1024, 0, stream>>>(envPart, ssimPart, (float*)d_out);
}